// Round 6
// baseline (27.943 us; speedup 1.0000x reference)
//
#include <hip/hip_runtime.h>

#define FEAT  41024
#define NF4   (FEAT / 4)   // 10256 float4s per row = 512*20 + 16
#define NROWS 512
#define NBINS 8            // layer-1 partial bins (indexed by row&7 ~ XCD)

// ---------------------------------------------------------------------------
// Kernel 1: one block per output row (512 blocks x 512 threads).
// Computes h[row] = relu(W@x + b) entirely in-block, then folds layer 1:
// lanes 0..31 atomicAdd h[row] * W1[o, row] into bins[row&7][o].
// Plain relaxed atomics (device-scope by default) — no acq_rel fences.
// ---------------------------------------------------------------------------
__global__ __launch_bounds__(512) void halfkp_matvec_l1(
    const float* __restrict__ x,
    const float* __restrict__ W_my,  const float* __restrict__ b_my,
    const float* __restrict__ W_opp, const float* __restrict__ b_opp,
    const float* __restrict__ W1,
    float* __restrict__ bins)        // [NBINS][32], zeroed each launch
{
    const int row = blockIdx.x;
    const int tid = threadIdx.x;

    const float4* __restrict__ W4 =
        (const float4*)(row < 256 ? W_my : W_opp) + (size_t)(row & 255) * NF4;
    const float4* __restrict__ x4 =
        (const float4*)x + (row < 256 ? 0 : NF4);

    float a0 = 0.f, a1 = 0.f, a2 = 0.f, a3 = 0.f;
    int i = tid;
    #pragma unroll
    for (int k = 0; k < 5; ++k) {   // 5 iters x 4 slices x 512 thr = 10240 f4
        float4 w0 = W4[i       ]; float4 v0 = x4[i       ];
        float4 w1 = W4[i +  512]; float4 v1 = x4[i +  512];
        float4 w2 = W4[i + 1024]; float4 v2 = x4[i + 1024];
        float4 w3 = W4[i + 1536]; float4 v3 = x4[i + 1536];
        a0 += w0.x*v0.x + w0.y*v0.y + w0.z*v0.z + w0.w*v0.w;
        a1 += w1.x*v1.x + w1.y*v1.y + w1.z*v1.z + w1.w*v1.w;
        a2 += w2.x*v2.x + w2.y*v2.y + w2.z*v2.z + w2.w*v2.w;
        a3 += w3.x*v3.x + w3.y*v3.y + w3.z*v3.z + w3.w*v3.w;
        i += 2048;
    }
    if (tid < 16) {  // remainder f4 indices 10240..10255
        float4 w = W4[10240 + tid]; float4 v = x4[10240 + tid];
        a0 += w.x*v.x + w.y*v.y + w.z*v.z + w.w*v.w;
    }

    float acc = (a0 + a1) + (a2 + a3);
    #pragma unroll
    for (int off = 32; off > 0; off >>= 1)
        acc += __shfl_down(acc, off, 64);

    __shared__ float red[8];
    if ((tid & 63) == 0) red[tid >> 6] = acc;
    __syncthreads();

    __shared__ float hval;
    if (tid == 0) {
        float s = red[0] + red[1] + red[2] + red[3]
                + red[4] + red[5] + red[6] + red[7]
                + ((row < 256) ? b_my[row] : b_opp[row - 256]);
        hval = s > 0.f ? s : 0.f;
    }
    __syncthreads();

    // layer-1 fold: h[row] contributes h*W1[o][row] to every output o
    if (tid < 32) {
        float v = hval * W1[tid * 512 + row];   // W1 column `row` (L2-hot)
        atomicAdd(&bins[(row & (NBINS - 1)) * 32 + tid], v);
    }
}

// ---------------------------------------------------------------------------
// Kernel 2: tiny tail — sum bins -> relu -> 32x32 -> relu -> 1.
// One block, 64 threads; reads ~5.3 KB total.
// ---------------------------------------------------------------------------
__global__ __launch_bounds__(64) void mlp_tail(
    const float* __restrict__ bins,
    const float* __restrict__ b1,
    const float* __restrict__ W2, const float* __restrict__ b2,
    const float* __restrict__ W3, const float* __restrict__ b3,
    float* __restrict__ out)
{
    __shared__ float h1[32];
    __shared__ float h2[32];
    const int t = threadIdx.x;

    if (t < 32) {
        float s = b1[t];
        #pragma unroll
        for (int g = 0; g < NBINS; ++g)
            s += bins[g * 32 + t];
        h1[t] = s > 0.f ? s : 0.f;
    }
    __syncthreads();

    if (t < 32) {
        float s = b2[t];
        #pragma unroll 8
        for (int k = 0; k < 32; ++k)
            s += W2[t * 32 + k] * h1[k];
        h2[t] = s > 0.f ? s : 0.f;
    }
    __syncthreads();

    if (t == 0) {
        float s = b3[0];
        #pragma unroll 8
        for (int k = 0; k < 32; ++k)
            s += W3[k] * h2[k];
        out[0] = s;
    }
}

extern "C" void kernel_launch(void* const* d_in, const int* in_sizes, int n_in,
                              void* d_out, int out_size, void* d_ws, size_t ws_size,
                              hipStream_t stream)
{
    const float* x     = (const float*)d_in[0];
    const float* W_my  = (const float*)d_in[1];
    const float* b_my  = (const float*)d_in[2];
    const float* W_opp = (const float*)d_in[3];
    const float* b_opp = (const float*)d_in[4];
    const float* W1    = (const float*)d_in[5];
    const float* b1    = (const float*)d_in[6];
    const float* W2    = (const float*)d_in[7];
    const float* b2    = (const float*)d_in[8];
    const float* W3    = (const float*)d_in[9];
    const float* b3    = (const float*)d_in[10];

    float* out  = (float*)d_out;
    float* bins = (float*)d_ws;   // NBINS*32 floats

    hipMemsetAsync(bins, 0, NBINS * 32 * sizeof(float), stream);
    halfkp_matvec_l1<<<NROWS, 512, 0, stream>>>(x, W_my, b_my, W_opp, b_opp,
                                                W1, bins);
    mlp_tail<<<1, 64, 0, stream>>>(bins, b1, W2, b2, W3, b3, out);
}

// Round 7
// 22.612 us; speedup vs baseline: 1.2358x; 1.2358x over previous
//
#include <hip/hip_runtime.h>

#define FEAT  41024
#define NF4   (FEAT / 4)    // 10256 float4s per full row
#define QF4   (NF4 / 4)     // 2564 float4s per quarter-row = 256*10 + 4
#define NBLK  2048          // one block per quarter-row

// ---------------------------------------------------------------------------
// Kernel 1: quarter-row partial dot products of the two 256x41024 matvecs.
// 2048 blocks x 256 threads (~8 blocks/CU resident -> ~24+ waves/CU),
// float4 loads, 4 independent accumulators. Plain stores of partials.
// ---------------------------------------------------------------------------
__global__ __launch_bounds__(256) void halfkp_matvec_part(
    const float* __restrict__ x,
    const float* __restrict__ W_my,
    const float* __restrict__ W_opp,
    float* __restrict__ partial)
{
    const int b   = blockIdx.x;
    const int tid = threadIdx.x;
    const int row = b >> 2;       // 0..511
    const int q   = b & 3;        // quarter index

    const float4* __restrict__ W4 =
        (const float4*)(row < 256 ? W_my : W_opp)
        + (size_t)(row & 255) * NF4 + (size_t)q * QF4;
    const float4* __restrict__ x4 =
        (const float4*)x + (row < 256 ? 0 : NF4) + (size_t)q * QF4;

    float a0 = 0.f, a1 = 0.f, a2 = 0.f, a3 = 0.f;
    int i = tid;
    #pragma unroll
    for (int k = 0; k < 2; ++k) {   // 2 x 4 x 256 = 2048 f4
        float4 w0 = W4[i      ]; float4 v0 = x4[i      ];
        float4 w1 = W4[i + 256]; float4 v1 = x4[i + 256];
        float4 w2 = W4[i + 512]; float4 v2 = x4[i + 512];
        float4 w3 = W4[i + 768]; float4 v3 = x4[i + 768];
        a0 += w0.x*v0.x + w0.y*v0.y + w0.z*v0.z + w0.w*v0.w;
        a1 += w1.x*v1.x + w1.y*v1.y + w1.z*v1.z + w1.w*v1.w;
        a2 += w2.x*v2.x + w2.y*v2.y + w2.z*v2.z + w2.w*v2.w;
        a3 += w3.x*v3.x + w3.y*v3.y + w3.z*v3.z + w3.w*v3.w;
        i += 1024;
    }
    {   // f4 indices 2048..2559
        float4 w0 = W4[2048 + tid]; float4 v0 = x4[2048 + tid];
        float4 w1 = W4[2304 + tid]; float4 v1 = x4[2304 + tid];
        a0 += w0.x*v0.x + w0.y*v0.y + w0.z*v0.z + w0.w*v0.w;
        a1 += w1.x*v1.x + w1.y*v1.y + w1.z*v1.z + w1.w*v1.w;
    }
    if (tid < 4) {  // remainder f4 indices 2560..2563
        float4 w = W4[2560 + tid]; float4 v = x4[2560 + tid];
        a2 += w.x*v.x + w.y*v.y + w.z*v.z + w.w*v.w;
    }

    float acc = (a0 + a1) + (a2 + a3);
    #pragma unroll
    for (int off = 32; off > 0; off >>= 1)
        acc += __shfl_down(acc, off, 64);

    __shared__ float red[4];
    if ((tid & 63) == 0) red[tid >> 6] = acc;
    __syncthreads();
    if (tid == 0)
        partial[b] = red[0] + red[1] + red[2] + red[3];
}

// ---------------------------------------------------------------------------
// Kernel 2: assemble h = relu(sum of 4 partials + bias), then 512->32->32->1.
// One block x 1024 threads; W1 preloaded to registers; float4 partial reads.
// ---------------------------------------------------------------------------
__global__ __launch_bounds__(1024) void mlp_head(
    const float* __restrict__ partial,
    const float* __restrict__ b_my, const float* __restrict__ b_opp,
    const float* __restrict__ W1,  const float* __restrict__ b1,
    const float* __restrict__ W2,  const float* __restrict__ b2,
    const float* __restrict__ W3,  const float* __restrict__ b3,
    float* __restrict__ out)
{
    __shared__ float hs[512];
    __shared__ float h1[32];
    __shared__ float h2[32];

    const int tid = threadIdx.x;
    const int o = tid >> 5;   // 0..31
    const int j = tid & 31;   // 0..31

    // preload W1 slice into registers (independent of partials)
    float w[16];
    #pragma unroll
    for (int k = 0; k < 16; ++k)
        w[k] = W1[o * 512 + j + 32 * k];

    if (tid < 512) {
        float4 p = ((const float4*)partial)[tid];
        float bias = (tid < 256) ? b_my[tid] : b_opp[tid - 256];
        float s = (p.x + p.y) + (p.z + p.w) + bias;
        hs[tid] = s > 0.f ? s : 0.f;
    }
    __syncthreads();

    float acc = 0.f;
    #pragma unroll
    for (int k = 0; k < 16; ++k)
        acc += w[k] * hs[j + 32 * k];
    acc += __shfl_down(acc, 16, 32);
    acc += __shfl_down(acc,  8, 32);
    acc += __shfl_down(acc,  4, 32);
    acc += __shfl_down(acc,  2, 32);
    acc += __shfl_down(acc,  1, 32);
    if (j == 0) {
        float s = acc + b1[o];
        h1[o] = s > 0.f ? s : 0.f;
    }
    __syncthreads();

    if (tid < 32) {
        float s = b2[tid];
        #pragma unroll 8
        for (int k = 0; k < 32; ++k)
            s += W2[tid * 32 + k] * h1[k];
        h2[tid] = s > 0.f ? s : 0.f;
    }
    __syncthreads();

    if (tid == 0) {
        float s = b3[0];
        #pragma unroll 8
        for (int k = 0; k < 32; ++k)
            s += W3[k] * h2[k];
        out[0] = s;
    }
}

extern "C" void kernel_launch(void* const* d_in, const int* in_sizes, int n_in,
                              void* d_out, int out_size, void* d_ws, size_t ws_size,
                              hipStream_t stream)
{
    const float* x     = (const float*)d_in[0];
    const float* W_my  = (const float*)d_in[1];
    const float* b_my  = (const float*)d_in[2];
    const float* W_opp = (const float*)d_in[3];
    const float* b_opp = (const float*)d_in[4];
    const float* W1    = (const float*)d_in[5];
    const float* b1    = (const float*)d_in[6];
    const float* W2    = (const float*)d_in[7];
    const float* b2    = (const float*)d_in[8];
    const float* W3    = (const float*)d_in[9];
    const float* b3    = (const float*)d_in[10];

    float* out     = (float*)d_out;
    float* partial = (float*)d_ws;   // 2048 floats

    halfkp_matvec_part<<<NBLK, 256, 0, stream>>>(x, W_my, W_opp, partial);
    mlp_head<<<1, 1024, 0, stream>>>(partial, b_my, b_opp,
                                     W1, b1, W2, b2, W3, b3, out);
}